// Round 2
// baseline (1258.456 us; speedup 1.0000x reference)
//
#include <hip/hip_runtime.h>
#include <hip/hip_bf16.h>

#define S_ 1024
#define D_ 1024
#define H_ 16
#define DQ_ 64
#define DV_ 32

typedef __attribute__((ext_vector_type(8))) short bf16x8;
typedef __attribute__((ext_vector_type(4))) float f32x4;

static __device__ __forceinline__ float bf2f(unsigned short u) {
    union { unsigned int i; float f; } v; v.i = ((unsigned int)u) << 16; return v.f;
}
static __device__ __forceinline__ unsigned short f2bf(float f) {
    union { float f; unsigned int i; } v; v.f = f;
    unsigned int x = v.i;
    unsigned int r = x + 0x7fffu + ((x >> 16) & 1u);
    return (unsigned short)(r >> 16);
}
static __device__ __forceinline__ f32x4 mfma16(bf16x8 a, bf16x8 b, f32x4 c) {
    return __builtin_amdgcn_mfma_f32_16x16x32_bf16(a, b, c, 0, 0, 0);
}

// ---------------------------------------------------------------------------
// Dtype probe: flag=1 if raw data is bf16, 0 if fp32.
// bf16 N(0,1) data: exponent byte of every 16-bit word is in ~[117,131].
// fp32 data read at even 16-bit offsets gives mantissa bits (uniform) there.
// ---------------------------------------------------------------------------
__global__ void k_detect(const unsigned short* __restrict__ X, int* __restrict__ flag) {
    int tid = threadIdx.x;               // 64 threads
    unsigned short u = X[2 * tid];
    int e = (u >> 7) & 0xFF;
    bool sane = (e >= 100 && e <= 150) || ((u & 0x7FFFu) == 0);
    unsigned long long m = __ballot(sane);
    if (tid == 0) *flag = (__popcll(m) >= 40) ? 1 : 0;
}

// src (fp32 or bf16 per flag) -> canonical bf16
__global__ void k_cvt(const void* __restrict__ src, unsigned short* __restrict__ dst,
                      int n, const int* __restrict__ flag) {
    int i = blockIdx.x * 256 + threadIdx.x;
    if (i >= n) return;
    int fl = *flag;
    dst[i] = fl ? ((const unsigned short*)src)[i] : f2bf(((const float*)src)[i]);
}

// src (fp32 or bf16 per flag) -> canonical fp32 (biases)
__global__ void k_cvt_f(const void* __restrict__ src, float* __restrict__ dst,
                        int n, const int* __restrict__ flag) {
    int i = blockIdx.x * 256 + threadIdx.x;
    if (i >= n) return;
    int fl = *flag;
    dst[i] = fl ? bf2f(((const unsigned short*)src)[i]) : ((const float*)src)[i];
}

// ---------------------------------------------------------------------------
// Weight transpose + convert: src[K][N] (fp32/bf16) -> dst[N][K] bf16.
// ---------------------------------------------------------------------------
__global__ void k_transpose(const void* __restrict__ src,
                            unsigned short* __restrict__ dst, int K, int N,
                            const int* __restrict__ flag) {
    __shared__ unsigned short t[32][33];
    int fl = *flag;
    int n0 = blockIdx.x * 32, k0 = blockIdx.y * 32;
    int tx = threadIdx.x, ty = threadIdx.y;  // blockDim (32,8)
    for (int i = ty; i < 32; i += 8) {
        size_t idx = (size_t)(k0 + i) * N + n0 + tx;
        t[i][tx] = fl ? ((const unsigned short*)src)[idx]
                      : f2bf(((const float*)src)[idx]);
    }
    __syncthreads();
    for (int i = ty; i < 32; i += 8)
        dst[(size_t)(n0 + i) * K + k0 + tx] = t[tx][i];
}

// ---------------------------------------------------------------------------
// Fused QKV projection GEMM.  Xb[4096x1024] @ {Wq,Wk,Wv} (+bias).
// Block: 256 thr = 4 waves. Block tile: 16(M) x 64(N); wave tile 16x16.
// Outputs: q_l,k_l [b][h][s][64] bf16; vT [b][h][dv][1024] bf16.
// ---------------------------------------------------------------------------
__global__ __launch_bounds__(256)
void k_qkv(const unsigned short* __restrict__ Xb,
           const unsigned short* __restrict__ WqT,
           const unsigned short* __restrict__ WkT,
           const unsigned short* __restrict__ WvT,
           const float* __restrict__ bias_f,  // [0,1024)=bq [1024,2048)=bk [2048,2560)=bv
           unsigned short* __restrict__ q_l,
           unsigned short* __restrict__ k_l,
           unsigned short* __restrict__ vT) {
    int wave = threadIdx.x >> 6;
    int lane = threadIdx.x & 63;
    int m = lane & 15, quad = lane >> 4;
    int row0 = blockIdx.y * 16;
    int col0 = blockIdx.x * 64 + wave * 16;  // global col in [0,2560)

    const unsigned short* BT; int cseg; const float* bias;
    if (col0 < 1024)      { BT = WqT; cseg = col0;        bias = bias_f; }
    else if (col0 < 2048) { BT = WkT; cseg = col0 - 1024; bias = bias_f + 1024; }
    else                  { BT = WvT; cseg = col0 - 2048; bias = bias_f + 2048; }

    const unsigned short* arow = Xb + (size_t)(row0 + m) * D_;
    const unsigned short* brow = BT + (size_t)(cseg + m) * D_;
    f32x4 acc = {0.f, 0.f, 0.f, 0.f};
#pragma unroll 4
    for (int k = 0; k < D_; k += 32) {
        bf16x8 a = *(const bf16x8*)(arow + k + quad * 8);
        bf16x8 b = *(const bf16x8*)(brow + k + quad * 8);
        acc = mfma16(a, b, acc);
    }

    int cn = lane & 15;                      // C col within tile
    int col = col0 + cn;
    float bval = bias[cseg + cn];
#pragma unroll
    for (int j = 0; j < 4; ++j) {
        int row = row0 + quad * 4 + j;
        int bb = row >> 10, ss = row & 1023;
        unsigned short o = f2bf(acc[j] + bval);
        if (col < 1024) {
            int h = col >> 6, d = col & 63;
            q_l[(((size_t)(bb * H_ + h)) * S_ + ss) * DQ_ + d] = o;
        } else if (col < 2048) {
            int c = col - 1024; int h = c >> 6, d = c & 63;
            k_l[(((size_t)(bb * H_ + h)) * S_ + ss) * DQ_ + d] = o;
        } else {
            int c = col - 2048; int h = c >> 5, dv = c & 31;
            vT[(((size_t)(bb * H_ + h)) * DV_ + dv) * S_ + ss] = o;
        }
    }
}

// ---------------------------------------------------------------------------
// Attention: block = one (b,h) x one 64-row q tile; 4 waves, wave = 16 q rows.
// Pass 1: online row max/sum (fwd & bwd). Pass 2: recompute scores, write
// probs (dtype per flag), fused PV via LDS C->A layout round trip.
// ---------------------------------------------------------------------------
__global__ __launch_bounds__(256)
void k_attn(const unsigned short* __restrict__ q_l,
            const unsigned short* __restrict__ k_l,
            const unsigned short* __restrict__ vT,
            unsigned short* __restrict__ probs_b,  // bf16 view (flag=1)
            float* __restrict__ probs_f,           // fp32 view (flag=0)
            unsigned short* __restrict__ Y,        // [b][s][1024] bf16
            const int* __restrict__ flag) {
    __shared__ __align__(16) unsigned short pls[4][2][16][40];
    int fl = *flag;
    int wave = threadIdx.x >> 6, lane = threadIdx.x & 63;
    int m = lane & 15, quad = lane >> 4;
    int bh = blockIdx.x;
    int q0 = blockIdx.y * 64 + wave * 16;
    int qt = q0 >> 4;

    const unsigned short* qp = q_l + (size_t)bh * S_ * DQ_;
    const unsigned short* kp = k_l + (size_t)bh * S_ * DQ_;
    const unsigned short* vp = vT  + (size_t)bh * DV_ * S_;

    bf16x8 qa0 = *(const bf16x8*)(qp + (size_t)(q0 + m) * DQ_ + quad * 8);
    bf16x8 qa1 = *(const bf16x8*)(qp + (size_t)(q0 + m) * DQ_ + 32 + quad * 8);

    float mF[4], lF[4], mB[4], lB[4];
#pragma unroll
    for (int j = 0; j < 4; ++j) { mF[j] = -1e30f; lF[j] = 0.f; mB[j] = -1e30f; lB[j] = 0.f; }

    // ---- Pass 1: stats ----
    for (int kt = 0; kt < 64; ++kt) {
        bool actF = (kt <= qt), actB = (kt >= qt);  // wave-uniform
        const unsigned short* krow = kp + (size_t)(kt * 16 + m) * DQ_;
        bf16x8 kb0 = *(const bf16x8*)(krow + quad * 8);
        bf16x8 kb1 = *(const bf16x8*)(krow + 32 + quad * 8);
        f32x4 s = {0.f, 0.f, 0.f, 0.f};
        s = mfma16(qa0, kb0, s);
        s = mfma16(qa1, kb1, s);
        int cg = kt * 16 + m;
#pragma unroll
        for (int j = 0; j < 4; ++j) {
            float sv = fminf(fmaxf(s[j] * 0.125f, -80.f), 80.f);
            int rg = q0 + quad * 4 + j;
            if (actF) {
                float sf = (cg <= rg) ? sv : -1e30f;
                float tmax = sf;
                tmax = fmaxf(tmax, __shfl_xor(tmax, 1, 64));
                tmax = fmaxf(tmax, __shfl_xor(tmax, 2, 64));
                tmax = fmaxf(tmax, __shfl_xor(tmax, 4, 64));
                tmax = fmaxf(tmax, __shfl_xor(tmax, 8, 64));
                float nm = fmaxf(mF[j], tmax);
                float ts = __expf(sf - nm);
                ts += __shfl_xor(ts, 1, 64);
                ts += __shfl_xor(ts, 2, 64);
                ts += __shfl_xor(ts, 4, 64);
                ts += __shfl_xor(ts, 8, 64);
                lF[j] = lF[j] * __expf(mF[j] - nm) + ts;
                mF[j] = nm;
            }
            if (actB) {
                float sf = (cg >= rg) ? sv : -1e30f;
                float tmax = sf;
                tmax = fmaxf(tmax, __shfl_xor(tmax, 1, 64));
                tmax = fmaxf(tmax, __shfl_xor(tmax, 2, 64));
                tmax = fmaxf(tmax, __shfl_xor(tmax, 4, 64));
                tmax = fmaxf(tmax, __shfl_xor(tmax, 8, 64));
                float nm = fmaxf(mB[j], tmax);
                float ts = __expf(sf - nm);
                ts += __shfl_xor(ts, 1, 64);
                ts += __shfl_xor(ts, 2, 64);
                ts += __shfl_xor(ts, 4, 64);
                ts += __shfl_xor(ts, 8, 64);
                lB[j] = lB[j] * __expf(mB[j] - nm) + ts;
                mB[j] = nm;
            }
        }
    }
    float rF[4], rB[4];
#pragma unroll
    for (int j = 0; j < 4; ++j) {
        rF[j] = 1.f / fmaxf(lF[j], 1e-30f);
        rB[j] = 1.f / fmaxf(lB[j], 1e-30f);
    }

    // ---- Pass 2: write probs + fused PV ----
    f32x4 accF0 = {0.f,0.f,0.f,0.f}, accF1 = {0.f,0.f,0.f,0.f};
    f32x4 accB0 = {0.f,0.f,0.f,0.f}, accB1 = {0.f,0.f,0.f,0.f};
    size_t pbase = (size_t)bh * S_ * 2 * S_;

    for (int ktp = 0; ktp < 32; ++ktp) {
#pragma unroll
        for (int hh = 0; hh < 2; ++hh) {
            int kt = ktp * 2 + hh;
            const unsigned short* krow = kp + (size_t)(kt * 16 + m) * DQ_;
            bf16x8 kb0 = *(const bf16x8*)(krow + quad * 8);
            bf16x8 kb1 = *(const bf16x8*)(krow + 32 + quad * 8);
            f32x4 s = {0.f, 0.f, 0.f, 0.f};
            s = mfma16(qa0, kb0, s);
            s = mfma16(qa1, kb1, s);
            int cg = kt * 16 + m;
#pragma unroll
            for (int j = 0; j < 4; ++j) {
                int rr = quad * 4 + j;
                int rg = q0 + rr;
                float sv = fminf(fmaxf(s[j] * 0.125f, -80.f), 80.f);
                float pF = (cg <= rg) ? __expf(sv - mF[j]) * rF[j] : 0.f;
                float pB = (cg >= rg) ? __expf(sv - mB[j]) * rB[j] : 0.f;
                unsigned short pf16 = f2bf(pF), pb16 = f2bf(pB);
                size_t oF = pbase + (size_t)rg * 2048 + cg;
                size_t oB = oF + 1024;
                if (fl) { probs_b[oF] = pf16; probs_b[oB] = pb16; }
                else    { probs_f[oF] = pF;   probs_f[oB] = pB; }
                pls[wave][0][rr][hh * 16 + m] = pf16;
                pls[wave][1][rr][hh * 16 + m] = pb16;
            }
        }
        __syncthreads();
        bf16x8 aF = *(const bf16x8*)&pls[wave][0][m][quad * 8];
        bf16x8 aB = *(const bf16x8*)&pls[wave][1][m][quad * 8];
        const unsigned short* vrow = vp + (size_t)m * S_ + ktp * 32 + quad * 8;
        bf16x8 bv0 = *(const bf16x8*)(vrow);
        bf16x8 bv1 = *(const bf16x8*)(vrow + 16 * S_);
        accF0 = mfma16(aF, bv0, accF0);
        accF1 = mfma16(aF, bv1, accF1);
        accB0 = mfma16(aB, bv0, accB0);
        accB1 = mfma16(aB, bv1, accB1);
        __syncthreads();
    }

    int b_ = bh >> 4, h_ = bh & 15;
#pragma unroll
    for (int j = 0; j < 4; ++j) {
        int rg = q0 + quad * 4 + j;
        size_t yb = ((size_t)b_ * S_ + rg) * 1024 + h_ * 32;
        Y[yb + m]            = f2bf(accF0[j]);
        Y[yb + 16 + m]       = f2bf(accF1[j]);
        Y[yb + 512 + m]      = f2bf(accB0[j]);
        Y[yb + 512 + 16 + m] = f2bf(accB1[j]);
    }
}

// ---------------------------------------------------------------------------
// Output projection: Y[4096x1024] @ Wo + bo -> out (dtype per flag).
// ---------------------------------------------------------------------------
__global__ __launch_bounds__(256)
void k_out(const unsigned short* __restrict__ Y,
           const unsigned short* __restrict__ WoT,
           const float* __restrict__ bo,
           unsigned short* __restrict__ out_b,
           float* __restrict__ out_f,
           const int* __restrict__ flag) {
    int fl = *flag;
    int wave = threadIdx.x >> 6;
    int lane = threadIdx.x & 63;
    int m = lane & 15, quad = lane >> 4;
    int row0 = blockIdx.y * 16;
    int col0 = blockIdx.x * 64 + wave * 16;

    const unsigned short* arow = Y   + (size_t)(row0 + m) * 1024;
    const unsigned short* brow = WoT + (size_t)(col0 + m) * 1024;
    f32x4 acc = {0.f, 0.f, 0.f, 0.f};
#pragma unroll 4
    for (int k = 0; k < 1024; k += 32) {
        bf16x8 a = *(const bf16x8*)(arow + k + quad * 8);
        bf16x8 b = *(const bf16x8*)(brow + k + quad * 8);
        acc = mfma16(a, b, acc);
    }
    int col = col0 + (lane & 15);
    float bval = bo[col];
#pragma unroll
    for (int j = 0; j < 4; ++j) {
        int row = row0 + quad * 4 + j;
        float v = acc[j] + bval;
        if (fl) out_b[(size_t)row * 1024 + col] = f2bf(v);
        else    out_f[(size_t)row * 1024 + col] = v;
    }
}

// ---------------------------------------------------------------------------
extern "C" void kernel_launch(void* const* d_in, const int* in_sizes, int n_in,
                              void* d_out, int out_size, void* d_ws, size_t ws_size,
                              hipStream_t stream) {
    const void* X  = d_in[0];
    const void* Wq = d_in[1];
    const void* bq = d_in[2];
    const void* Wk = d_in[3];
    const void* bk = d_in[4];
    const void* Wv = d_in[5];
    const void* bv = d_in[6];
    const void* Wo = d_in[7];
    const void* bo = d_in[8];

    unsigned short* ws  = (unsigned short*)d_ws;
    unsigned short* Xb  = ws;               //  4,194,304 bf16
    unsigned short* q_l = ws + 4194304;     //  4,194,304
    unsigned short* k_l = ws + 8388608;     //  4,194,304
    unsigned short* vT  = ws + 12582912;    //  2,097,152
    unsigned short* Y   = ws + 14680064;    //  4,194,304
    unsigned short* WqT = ws + 18874368;    //  1,048,576
    unsigned short* WkT = ws + 19922944;    //  1,048,576
    unsigned short* WvT = ws + 20971520;    //    524,288
    unsigned short* WoT = ws + 21495808;    //  1,048,576
    float*  bias_f = (float*)(ws + 22544384);  // 3584 floats: bq,bk,bv,bo
    int*    flag   = (int*)(bias_f + 3584);    // end ~45.1 MB

    k_detect<<<1, 64, 0, stream>>>((const unsigned short*)X, flag);

    dim3 tb(32, 8);
    k_transpose<<<dim3(32, 32), tb, 0, stream>>>(Wq, WqT, 1024, 1024, flag);
    k_transpose<<<dim3(32, 32), tb, 0, stream>>>(Wk, WkT, 1024, 1024, flag);
    k_transpose<<<dim3(16, 32), tb, 0, stream>>>(Wv, WvT, 1024, 512, flag);
    k_transpose<<<dim3(32, 32), tb, 0, stream>>>(Wo, WoT, 1024, 1024, flag);

    k_cvt<<<16384, 256, 0, stream>>>(X, Xb, 4194304, flag);
    k_cvt_f<<<4, 256, 0, stream>>>(bq, bias_f,        1024, flag);
    k_cvt_f<<<4, 256, 0, stream>>>(bk, bias_f + 1024, 1024, flag);
    k_cvt_f<<<2, 256, 0, stream>>>(bv, bias_f + 2048,  512, flag);
    k_cvt_f<<<4, 256, 0, stream>>>(bo, bias_f + 2560, 1024, flag);

    k_qkv<<<dim3(40, 256), 256, 0, stream>>>(Xb, WqT, WkT, WvT, bias_f, q_l, k_l, vT);
    k_attn<<<dim3(64, 16), 256, 0, stream>>>(q_l, k_l, vT,
                                             (unsigned short*)d_out + 4194304,
                                             (float*)d_out + 4194304, Y, flag);
    k_out<<<dim3(16, 256), 256, 0, stream>>>(Y, WoT, bias_f + 2560,
                                             (unsigned short*)d_out, (float*)d_out, flag);
}

// Round 3
// 1088.485 us; speedup vs baseline: 1.1562x; 1.1562x over previous
//
#include <hip/hip_runtime.h>
#include <hip/hip_bf16.h>

#define S_ 1024
#define D_ 1024
#define H_ 16
#define DQ_ 64
#define DV_ 32

typedef __attribute__((ext_vector_type(8))) short bf16x8;
typedef __attribute__((ext_vector_type(4))) float f32x4;

static __device__ __forceinline__ float bf2f(unsigned short u) {
    union { unsigned int i; float f; } v; v.i = ((unsigned int)u) << 16; return v.f;
}
static __device__ __forceinline__ unsigned short f2bf(float f) {
    union { float f; unsigned int i; } v; v.f = f;
    unsigned int x = v.i;
    unsigned int r = x + 0x7fffu + ((x >> 16) & 1u);
    return (unsigned short)(r >> 16);
}
static __device__ __forceinline__ f32x4 mfma16(bf16x8 a, bf16x8 b, f32x4 c) {
    return __builtin_amdgcn_mfma_f32_16x16x32_bf16(a, b, c, 0, 0, 0);
}

// ---------------------------------------------------------------------------
// Dtype probe: flag=1 if raw data is bf16, 0 if fp32.
// ---------------------------------------------------------------------------
__global__ void k_detect(const unsigned short* __restrict__ X, int* __restrict__ flag) {
    int tid = threadIdx.x;               // 64 threads
    unsigned short u = X[2 * tid];
    int e = (u >> 7) & 0xFF;
    bool sane = (e >= 100 && e <= 150) || ((u & 0x7FFFu) == 0);
    unsigned long long m = __ballot(sane);
    if (tid == 0) *flag = (__popcll(m) >= 40) ? 1 : 0;
}

__global__ void k_cvt(const void* __restrict__ src, unsigned short* __restrict__ dst,
                      int n, const int* __restrict__ flag) {
    int i = blockIdx.x * 256 + threadIdx.x;
    if (i >= n) return;
    int fl = *flag;
    dst[i] = fl ? ((const unsigned short*)src)[i] : f2bf(((const float*)src)[i]);
}

__global__ void k_cvt_f(const void* __restrict__ src, float* __restrict__ dst,
                        int n, const int* __restrict__ flag) {
    int i = blockIdx.x * 256 + threadIdx.x;
    if (i >= n) return;
    int fl = *flag;
    dst[i] = fl ? bf2f(((const unsigned short*)src)[i]) : ((const float*)src)[i];
}

// ---------------------------------------------------------------------------
// Weight transpose + convert: src[K][N] (fp32/bf16) -> dst[N][K] bf16.
// ---------------------------------------------------------------------------
__global__ void k_transpose(const void* __restrict__ src,
                            unsigned short* __restrict__ dst, int K, int N,
                            const int* __restrict__ flag) {
    __shared__ unsigned short t[32][33];
    int fl = *flag;
    int n0 = blockIdx.x * 32, k0 = blockIdx.y * 32;
    int tx = threadIdx.x, ty = threadIdx.y;  // blockDim (32,8)
    for (int i = ty; i < 32; i += 8) {
        size_t idx = (size_t)(k0 + i) * N + n0 + tx;
        t[i][tx] = fl ? ((const unsigned short*)src)[idx]
                      : f2bf(((const float*)src)[idx]);
    }
    __syncthreads();
    for (int i = ty; i < 32; i += 8)
        dst[(size_t)(n0 + i) * K + k0 + tx] = t[tx][i];
}

// ---------------------------------------------------------------------------
// Fused QKV projection GEMM (unchanged from round 2).
// ---------------------------------------------------------------------------
__global__ __launch_bounds__(256)
void k_qkv(const unsigned short* __restrict__ Xb,
           const unsigned short* __restrict__ WqT,
           const unsigned short* __restrict__ WkT,
           const unsigned short* __restrict__ WvT,
           const float* __restrict__ bias_f,
           unsigned short* __restrict__ q_l,
           unsigned short* __restrict__ k_l,
           unsigned short* __restrict__ vT) {
    int wave = threadIdx.x >> 6;
    int lane = threadIdx.x & 63;
    int m = lane & 15, quad = lane >> 4;
    int row0 = blockIdx.y * 16;
    int col0 = blockIdx.x * 64 + wave * 16;

    const unsigned short* BT; int cseg; const float* bias;
    if (col0 < 1024)      { BT = WqT; cseg = col0;        bias = bias_f; }
    else if (col0 < 2048) { BT = WkT; cseg = col0 - 1024; bias = bias_f + 1024; }
    else                  { BT = WvT; cseg = col0 - 2048; bias = bias_f + 2048; }

    const unsigned short* arow = Xb + (size_t)(row0 + m) * D_;
    const unsigned short* brow = BT + (size_t)(cseg + m) * D_;
    f32x4 acc = {0.f, 0.f, 0.f, 0.f};
#pragma unroll 4
    for (int k = 0; k < D_; k += 32) {
        bf16x8 a = *(const bf16x8*)(arow + k + quad * 8);
        bf16x8 b = *(const bf16x8*)(brow + k + quad * 8);
        acc = mfma16(a, b, acc);
    }

    int cn = lane & 15;
    int col = col0 + cn;
    float bval = bias[cseg + cn];
#pragma unroll
    for (int j = 0; j < 4; ++j) {
        int row = row0 + quad * 4 + j;
        int bb = row >> 10, ss = row & 1023;
        unsigned short o = f2bf(acc[j] + bval);
        if (col < 1024) {
            int h = col >> 6, d = col & 63;
            q_l[(((size_t)(bb * H_ + h)) * S_ + ss) * DQ_ + d] = o;
        } else if (col < 2048) {
            int c = col - 1024; int h = c >> 6, d = c & 63;
            k_l[(((size_t)(bb * H_ + h)) * S_ + ss) * DQ_ + d] = o;
        } else {
            int c = col - 2048; int h = c >> 5, dv = c & 31;
            vT[(((size_t)(bb * H_ + h)) * DV_ + dv) * S_ + ss] = o;
        }
    }
}

// ---------------------------------------------------------------------------
// Attention (restructured): block = one (b,h) x 16 q-rows; 4 waves split the
// 1024-wide k dimension (256 cols each). Scores computed ONCE into registers.
// Row max/sum: 15 register fmax -> 4 shfl (quad) -> LDS cross-wave combine.
// Unnormalized e=exp(s-m) -> whole-row LDS buffer P[2][16][1032] (bf16),
// used for (a) coalesced float4 probs write (normalized on the fly) and
// (b) A-operand of PV MFMA (normalize accumulator by 1/l at epilogue).
// ---------------------------------------------------------------------------
__global__ __launch_bounds__(256)
void k_attn(const unsigned short* __restrict__ q_l,
            const unsigned short* __restrict__ k_l,
            const unsigned short* __restrict__ vT,
            unsigned short* __restrict__ probs_b,  // bf16 view (flag=1)
            float* __restrict__ probs_f,           // fp32 view (flag=0)
            unsigned short* __restrict__ Y,        // [b][s][1024] bf16
            const int* __restrict__ flag) {
    __shared__ __align__(16) unsigned short P[2][16][1032];  // [dir][qrow][col]
    __shared__ float redM[4][2][16];
    __shared__ float redL[4][2][16];
    int fl = *flag;
    int tid = threadIdx.x;
    int w = tid >> 6, lane = tid & 63;
    int m = lane & 15, quad = lane >> 4;
    int bh = blockIdx.x;
    int q0 = blockIdx.y * 16;
    int kbase = w * 256;

    const unsigned short* qp = q_l + (size_t)bh * S_ * DQ_;
    const unsigned short* kp = k_l + (size_t)bh * S_ * DQ_;
    const unsigned short* vp = vT  + (size_t)bh * DV_ * S_;

    bf16x8 qa0 = *(const bf16x8*)(qp + (size_t)(q0 + m) * DQ_ + quad * 8);
    bf16x8 qa1 = *(const bf16x8*)(qp + (size_t)(q0 + m) * DQ_ + 32 + quad * 8);

    // ---- scores once, into registers: sc[t][j], col = kbase+t*16+m, row = q0+quad*4+j
    float sc[16][4];
#pragma unroll
    for (int t = 0; t < 16; ++t) {
        const unsigned short* krow = kp + (size_t)((kbase >> 4) * 16 + t * 16 + m) * DQ_;
        bf16x8 kb0 = *(const bf16x8*)(krow + quad * 8);
        bf16x8 kb1 = *(const bf16x8*)(krow + 32 + quad * 8);
        f32x4 s = {0.f, 0.f, 0.f, 0.f};
        s = mfma16(qa0, kb0, s);
        s = mfma16(qa1, kb1, s);
#pragma unroll
        for (int j = 0; j < 4; ++j) sc[t][j] = s[j] * 0.125f;
    }

    // ---- per-row masked max: registers -> quad shfl -> LDS
#pragma unroll
    for (int j = 0; j < 4; ++j) {
        int row = quad * 4 + j;
        int r = q0 + row;
        float mF = -3e38f, mB = -3e38f;
#pragma unroll
        for (int t = 0; t < 16; ++t) {
            int c = kbase + t * 16 + m;
            float v = sc[t][j];
            mF = (c <= r) ? fmaxf(mF, v) : mF;
            mB = (c >= r) ? fmaxf(mB, v) : mB;
        }
        mF = fmaxf(mF, __shfl_xor(mF, 1, 64));
        mF = fmaxf(mF, __shfl_xor(mF, 2, 64));
        mF = fmaxf(mF, __shfl_xor(mF, 4, 64));
        mF = fmaxf(mF, __shfl_xor(mF, 8, 64));
        mB = fmaxf(mB, __shfl_xor(mB, 1, 64));
        mB = fmaxf(mB, __shfl_xor(mB, 2, 64));
        mB = fmaxf(mB, __shfl_xor(mB, 4, 64));
        mB = fmaxf(mB, __shfl_xor(mB, 8, 64));
        if (m == 0) { redM[w][0][row] = mF; redM[w][1][row] = mB; }
    }
    __syncthreads();

    // ---- e = exp(s - gmax) -> LDS P, partial sums -> LDS
#pragma unroll
    for (int j = 0; j < 4; ++j) {
        int row = quad * 4 + j;
        int r = q0 + row;
        float gmF = fmaxf(fmaxf(redM[0][0][row], redM[1][0][row]),
                          fmaxf(redM[2][0][row], redM[3][0][row]));
        float gmB = fmaxf(fmaxf(redM[0][1][row], redM[1][1][row]),
                          fmaxf(redM[2][1][row], redM[3][1][row]));
        float sF = 0.f, sB = 0.f;
#pragma unroll
        for (int t = 0; t < 16; ++t) {
            int c = kbase + t * 16 + m;
            float v = sc[t][j];
            float eF = (c <= r) ? __expf(v - gmF) : 0.f;
            float eB = (c >= r) ? __expf(v - gmB) : 0.f;
            sF += eF; sB += eB;
            P[0][row][c] = f2bf(eF);
            P[1][row][c] = f2bf(eB);
        }
        sF += __shfl_xor(sF, 1, 64);
        sF += __shfl_xor(sF, 2, 64);
        sF += __shfl_xor(sF, 4, 64);
        sF += __shfl_xor(sF, 8, 64);
        sB += __shfl_xor(sB, 1, 64);
        sB += __shfl_xor(sB, 2, 64);
        sB += __shfl_xor(sB, 4, 64);
        sB += __shfl_xor(sB, 8, 64);
        if (m == 0) { redL[w][0][row] = sF; redL[w][1][row] = sB; }
    }
    __syncthreads();

    // ---- coalesced probs write: 256 threads x 32 iters x float4
    size_t pbase = (size_t)bh << 21;  // bh * 1024 * 2048
#pragma unroll 4
    for (int i = 0; i < 32; ++i) {
        int row = i >> 1, dir = i & 1;
        int col4 = tid * 4;
        ushort4 ev = *(const ushort4*)&P[dir][row][col4];
        float l = redL[0][dir][row] + redL[1][dir][row] +
                  redL[2][dir][row] + redL[3][dir][row];
        float inv = 1.f / l;
        size_t off = pbase + (size_t)(q0 + row) * 2048 + (size_t)dir * 1024 + col4;
        if (fl) {
            ushort4 o;
            o.x = f2bf(bf2f(ev.x) * inv); o.y = f2bf(bf2f(ev.y) * inv);
            o.z = f2bf(bf2f(ev.z) * inv); o.w = f2bf(bf2f(ev.w) * inv);
            *(ushort4*)(probs_b + off) = o;
        } else {
            float4 o = { bf2f(ev.x) * inv, bf2f(ev.y) * inv,
                         bf2f(ev.z) * inv, bf2f(ev.w) * inv };
            *(float4*)(probs_f + off) = o;
        }
    }

    // ---- PV: wave = dir x dv-half; C[16 q x 16 dv], k over full 1024
    {
        int dir = w >> 1, half = w & 1;
        const unsigned short* vrow = vp + (size_t)(half * 16 + m) * S_;
        f32x4 acc0 = {0.f,0.f,0.f,0.f}, acc1 = {0.f,0.f,0.f,0.f};
#pragma unroll
        for (int it = 0; it < 32; it += 2) {
            bf16x8 a0 = *(const bf16x8*)&P[dir][m][it * 32 + quad * 8];
            bf16x8 b0 = *(const bf16x8*)(vrow + it * 32 + quad * 8);
            acc0 = mfma16(a0, b0, acc0);
            bf16x8 a1 = *(const bf16x8*)&P[dir][m][it * 32 + 32 + quad * 8];
            bf16x8 b1 = *(const bf16x8*)(vrow + it * 32 + 32 + quad * 8);
            acc1 = mfma16(a1, b1, acc1);
        }
        int b_ = bh >> 4, h_ = bh & 15;
#pragma unroll
        for (int j = 0; j < 4; ++j) {
            int row = quad * 4 + j;
            float l = redL[0][dir][row] + redL[1][dir][row] +
                      redL[2][dir][row] + redL[3][dir][row];
            float v = (acc0[j] + acc1[j]) / l;
            Y[((size_t)(b_ * 1024 + q0 + row)) * 1024 +
              dir * 512 + h_ * 32 + half * 16 + m] = f2bf(v);
        }
    }
}

// ---------------------------------------------------------------------------
// Output projection (unchanged from round 2).
// ---------------------------------------------------------------------------
__global__ __launch_bounds__(256)
void k_out(const unsigned short* __restrict__ Y,
           const unsigned short* __restrict__ WoT,
           const float* __restrict__ bo,
           unsigned short* __restrict__ out_b,
           float* __restrict__ out_f,
           const int* __restrict__ flag) {
    int fl = *flag;
    int wave = threadIdx.x >> 6;
    int lane = threadIdx.x & 63;
    int m = lane & 15, quad = lane >> 4;
    int row0 = blockIdx.y * 16;
    int col0 = blockIdx.x * 64 + wave * 16;

    const unsigned short* arow = Y   + (size_t)(row0 + m) * 1024;
    const unsigned short* brow = WoT + (size_t)(col0 + m) * 1024;
    f32x4 acc = {0.f, 0.f, 0.f, 0.f};
#pragma unroll 4
    for (int k = 0; k < 1024; k += 32) {
        bf16x8 a = *(const bf16x8*)(arow + k + quad * 8);
        bf16x8 b = *(const bf16x8*)(brow + k + quad * 8);
        acc = mfma16(a, b, acc);
    }
    int col = col0 + (lane & 15);
    float bval = bo[col];
#pragma unroll
    for (int j = 0; j < 4; ++j) {
        int row = row0 + quad * 4 + j;
        float v = acc[j] + bval;
        if (fl) out_b[(size_t)row * 1024 + col] = f2bf(v);
        else    out_f[(size_t)row * 1024 + col] = v;
    }
}

// ---------------------------------------------------------------------------
extern "C" void kernel_launch(void* const* d_in, const int* in_sizes, int n_in,
                              void* d_out, int out_size, void* d_ws, size_t ws_size,
                              hipStream_t stream) {
    const void* X  = d_in[0];
    const void* Wq = d_in[1];
    const void* bq = d_in[2];
    const void* Wk = d_in[3];
    const void* bk = d_in[4];
    const void* Wv = d_in[5];
    const void* bv = d_in[6];
    const void* Wo = d_in[7];
    const void* bo = d_in[8];

    unsigned short* ws  = (unsigned short*)d_ws;
    unsigned short* Xb  = ws;               //  4,194,304 bf16
    unsigned short* q_l = ws + 4194304;     //  4,194,304
    unsigned short* k_l = ws + 8388608;     //  4,194,304
    unsigned short* vT  = ws + 12582912;    //  2,097,152
    unsigned short* Y   = ws + 14680064;    //  4,194,304
    unsigned short* WqT = ws + 18874368;    //  1,048,576
    unsigned short* WkT = ws + 19922944;    //  1,048,576
    unsigned short* WvT = ws + 20971520;    //    524,288
    unsigned short* WoT = ws + 21495808;    //  1,048,576
    float*  bias_f = (float*)(ws + 22544384);  // 3584 floats
    int*    flag   = (int*)(bias_f + 3584);

    k_detect<<<1, 64, 0, stream>>>((const unsigned short*)X, flag);

    dim3 tb(32, 8);
    k_transpose<<<dim3(32, 32), tb, 0, stream>>>(Wq, WqT, 1024, 1024, flag);
    k_transpose<<<dim3(32, 32), tb, 0, stream>>>(Wk, WkT, 1024, 1024, flag);
    k_transpose<<<dim3(16, 32), tb, 0, stream>>>(Wv, WvT, 1024, 512, flag);
    k_transpose<<<dim3(32, 32), tb, 0, stream>>>(Wo, WoT, 1024, 1024, flag);

    k_cvt<<<16384, 256, 0, stream>>>(X, Xb, 4194304, flag);
    k_cvt_f<<<4, 256, 0, stream>>>(bq, bias_f,        1024, flag);
    k_cvt_f<<<4, 256, 0, stream>>>(bk, bias_f + 1024, 1024, flag);
    k_cvt_f<<<2, 256, 0, stream>>>(bv, bias_f + 2048,  512, flag);
    k_cvt_f<<<4, 256, 0, stream>>>(bo, bias_f + 2560, 1024, flag);

    k_qkv<<<dim3(40, 256), 256, 0, stream>>>(Xb, WqT, WkT, WvT, bias_f, q_l, k_l, vT);
    k_attn<<<dim3(64, 64), 256, 0, stream>>>(q_l, k_l, vT,
                                             (unsigned short*)d_out + 4194304,
                                             (float*)d_out + 4194304, Y, flag);
    k_out<<<dim3(16, 256), 256, 0, stream>>>(Y, WoT, bias_f + 2560,
                                             (unsigned short*)d_out, (float*)d_out, flag);
}